// Round 8
// baseline (99.227 us; speedup 1.0000x reference)
//
#include <hip/hip_runtime.h>
#include <math.h>

#define NODES 4096
#define FEATS 256
#define BATCH 1024
#define LR_C 0.5f
#define SIGMA_C 70.4f

typedef _Float16 f16x8 __attribute__((ext_vector_type(8)));
typedef float floatx4 __attribute__((ext_vector_type(4)));

__device__ __forceinline__ void get_params(int it, float& lr, float& r2, float& i2r2) {
    float decay = __expf(-(float)it * (SIGMA_C / 100000.0f));
    float radius = SIGMA_C * decay + 1e-6f;
    lr = LR_C * decay;
    r2 = radius * radius;
    i2r2 = 1.0f / (2.0f * r2);
}

// monotone float -> uint key; u64 key = (fkey << 32) | idx (ties -> smaller idx)
__device__ __forceinline__ unsigned fkey(float f) {
    unsigned u = __float_as_uint(f);
    return (u & 0x80000000u) ? ~u : (u | 0x80000000u);
}
__device__ __forceinline__ unsigned long long shfl_xor_u64(unsigned long long v, int mask) {
    unsigned lo = (unsigned)v, hi = (unsigned)(v >> 32);
    lo = __shfl_xor(lo, mask, 64);
    hi = __shfl_xor(hi, mask, 64);
    return ((unsigned long long)hi << 32) | lo;
}

// ---- K1 (blocks 0..511): fused GEMM1. fp32 X/W -> fp16 hi/lo split staged in LDS,
//      w2 accumulated in-loop, fp32-accurate sqd via 3-product split MFMA, per-row
//      in-wave min -> packed-u64 atomicMin(gmin). Tile 128b x 64n.
//      (blocks 512..575): XT build (X fp32 -> fp16 d-major transpose).
__global__ __launch_bounds__(256) void k_gemm1min(const float* __restrict__ X, const float* __restrict__ Wm,
                                                  unsigned long long* __restrict__ gmin,
                                                  _Float16* __restrict__ XT) {
    const int t = threadIdx.x;
    const int blk = blockIdx.x;
    if (blk >= 512) {  // ---- XT tail blocks
        __shared__ _Float16 T[64][72];
        const int blk2 = blk - 512;
        const int b0 = (blk2 & 15) * 64, d0 = (blk2 >> 4) * 64;
        {
            const int bl = t >> 2, dq = (t & 3) * 16;
            _Float16 h[16];
#pragma unroll
            for (int c = 0; c < 4; ++c) {
                float4 v = *(const float4*)&X[(size_t)(b0 + bl) * FEATS + d0 + dq + c * 4];
                h[c * 4 + 0] = (_Float16)v.x; h[c * 4 + 1] = (_Float16)v.y;
                h[c * 4 + 2] = (_Float16)v.z; h[c * 4 + 3] = (_Float16)v.w;
            }
#pragma unroll
            for (int c = 0; c < 16; ++c) T[bl][dq + c] = h[c];
        }
        __syncthreads();
        {
            const int dl = t >> 2, bq = (t & 3) * 16;
            union { _Float16 h[16]; float4 q[2]; } u;
#pragma unroll
            for (int c = 0; c < 16; ++c) u.h[c] = T[bq + c][dl];
            *(float4*)&XT[(size_t)(d0 + dl) * BATCH + b0 + bq] = u.q[0];
            *(float4*)&XT[(size_t)(d0 + dl) * BATCH + b0 + bq + 8] = u.q[1];
        }
        return;
    }
    __shared__ _Float16 Ah[128][40];
    __shared__ _Float16 Al[128][40];
    __shared__ _Float16 Bh[64][40];
    __shared__ _Float16 Bl[64][40];
    __shared__ float w2s[64];
    const int n0 = (blk & 63) * 64;
    const int b0 = (blk >> 6) * 128;
    const int wave = t >> 6, lane = t & 63;
    const int lm = lane & 15, quad = lane >> 4;
    const int arow = t >> 1, ako = (t & 1) * 16;   // A: 128 rows x 2 threads (16 k each)
    const int brow = t >> 2, bko = (t & 3) * 8;    // B: 64 rows x 4 threads (8 k each)
    float w2p = 0.0f;
    floatx4 acc[2][4] = {};
    for (int k0 = 0; k0 < FEATS; k0 += 32) {
        {   // stage A (X rows), split hi/lo
            union { _Float16 h[16]; float4 q[2]; } uh, ul;
#pragma unroll
            for (int c = 0; c < 4; ++c) {
                float4 v = *(const float4*)&X[(size_t)(b0 + arow) * FEATS + k0 + ako + c * 4];
                _Float16 h0 = (_Float16)v.x, h1 = (_Float16)v.y, h2 = (_Float16)v.z, h3 = (_Float16)v.w;
                uh.h[c * 4 + 0] = h0; uh.h[c * 4 + 1] = h1; uh.h[c * 4 + 2] = h2; uh.h[c * 4 + 3] = h3;
                ul.h[c * 4 + 0] = (_Float16)(v.x - (float)h0);
                ul.h[c * 4 + 1] = (_Float16)(v.y - (float)h1);
                ul.h[c * 4 + 2] = (_Float16)(v.z - (float)h2);
                ul.h[c * 4 + 3] = (_Float16)(v.w - (float)h3);
            }
            *(float4*)&Ah[arow][ako] = uh.q[0];
            *(float4*)&Ah[arow][ako + 8] = uh.q[1];
            *(float4*)&Al[arow][ako] = ul.q[0];
            *(float4*)&Al[arow][ako + 8] = ul.q[1];
        }
        {   // stage B (W rows), split hi/lo + w2 partial
            union { _Float16 h[8]; float4 q; } uh, ul;
#pragma unroll
            for (int c = 0; c < 2; ++c) {
                float4 v = *(const float4*)&Wm[(size_t)(n0 + brow) * FEATS + k0 + bko + c * 4];
                w2p += v.x * v.x + v.y * v.y + v.z * v.z + v.w * v.w;
                _Float16 h0 = (_Float16)v.x, h1 = (_Float16)v.y, h2 = (_Float16)v.z, h3 = (_Float16)v.w;
                uh.h[c * 4 + 0] = h0; uh.h[c * 4 + 1] = h1; uh.h[c * 4 + 2] = h2; uh.h[c * 4 + 3] = h3;
                ul.h[c * 4 + 0] = (_Float16)(v.x - (float)h0);
                ul.h[c * 4 + 1] = (_Float16)(v.y - (float)h1);
                ul.h[c * 4 + 2] = (_Float16)(v.z - (float)h2);
                ul.h[c * 4 + 3] = (_Float16)(v.w - (float)h3);
            }
            *(float4*)&Bh[brow][bko] = uh.q;
            *(float4*)&Bl[brow][bko] = ul.q;
        }
        __syncthreads();
        f16x8 ah[2], al[2], bh[4], bl[4];
#pragma unroll
        for (int i = 0; i < 2; ++i) {
            ah[i] = *(f16x8*)&Ah[wave * 32 + i * 16 + lm][quad * 8];
            al[i] = *(f16x8*)&Al[wave * 32 + i * 16 + lm][quad * 8];
        }
#pragma unroll
        for (int j = 0; j < 4; ++j) {
            bh[j] = *(f16x8*)&Bh[j * 16 + lm][quad * 8];
            bl[j] = *(f16x8*)&Bl[j * 16 + lm][quad * 8];
        }
#pragma unroll
        for (int i = 0; i < 2; ++i)
#pragma unroll
            for (int j = 0; j < 4; ++j) {
                acc[i][j] = __builtin_amdgcn_mfma_f32_16x16x32_f16(ah[i], bh[j], acc[i][j], 0, 0, 0);
                acc[i][j] = __builtin_amdgcn_mfma_f32_16x16x32_f16(ah[i], bl[j], acc[i][j], 0, 0, 0);
                acc[i][j] = __builtin_amdgcn_mfma_f32_16x16x32_f16(al[i], bh[j], acc[i][j], 0, 0, 0);
            }
        __syncthreads();
    }
    // w2[brow]: 4 threads per row hold disjoint k-stripe partials (consecutive lanes)
    w2p += __shfl_xor(w2p, 1, 64);
    w2p += __shfl_xor(w2p, 2, 64);
    if ((t & 3) == 0) w2s[brow] = w2p;
    __syncthreads();
#pragma unroll
    for (int i = 0; i < 2; ++i)
#pragma unroll
        for (int r = 0; r < 4; ++r) {
            const int row = b0 + wave * 32 + i * 16 + quad * 4 + r;
            unsigned long long m = 0xFFFFFFFFFFFFFFFFULL;
#pragma unroll
            for (int j = 0; j < 4; ++j) {
                float v = w2s[j * 16 + lm] - 2.0f * acc[i][j][r];
                unsigned long long k = ((unsigned long long)fkey(v) << 32) | (unsigned)(n0 + j * 16 + lm);
                if (k < m) m = k;
            }
#pragma unroll
            for (int mk = 1; mk < 16; mk <<= 1) {
                unsigned long long o = shfl_xor_u64(m, mk);
                if (o < m) m = o;
            }
            if (lm == 0) atomicMin(&gmin[row], m);
        }
}

// ---- K2: per-block 16-node stripe. Phase 0: bmu -> LDS, 64x64 fp16 lr-table (radius
//      folded in), out1 (blocks 0..3). Phase 1: synthesize full A (16x1024 lr_op) into
//      LDS once + Svec via LDS atomicAdd. Phase 2: barrier-free K-loop — A from LDS
//      (ds_read_b128), B straight from XT global (dwordx4 per frag), MFMA; fused
//      combine epilogue: out0 = Wm*(1 - Sv/B) + acc/B.
__global__ __launch_bounds__(256) void k_gemm2d(const unsigned long long* __restrict__ gmin,
                                                const int* __restrict__ itp,
                                                const _Float16* __restrict__ XT,
                                                const float* __restrict__ Wm,
                                                float* __restrict__ out0, float* __restrict__ out1) {
    __shared__ _Float16 As[16][1032];   // +8 pad
    __shared__ _Float16 T2h[4096];
    __shared__ int bmu_s[1024];
    __shared__ float Sv[16];
    const int t = threadIdx.x;
    const int blk = blockIdx.x;
    const int n0 = blk * 16;
    float lr, r2, i2r2;
    get_params(itp[0], lr, r2, i2r2);
#pragma unroll
    for (int i = 0; i < 4; ++i) bmu_s[t * 4 + i] = (int)(gmin[t * 4 + i] & 0xFFFFFFFFULL);
#pragma unroll
    for (int i = 0; i < 16; ++i) {
        int e = t * 16 + i;
        int di = e >> 6, dj = e & 63;
        int d2 = di * di + dj * dj;
        float val = ((float)d2 <= r2) ? lr * __expf(-(float)d2 * i2r2) : 0.0f;
        T2h[e] = (_Float16)val;
    }
    if (t < 16) Sv[t] = 0.0f;
    __syncthreads();
    if (blk < 4) out1[blk * 256 + t] = (float)bmu_s[blk * 256 + t];
    // phase 1: A synthesis (thread: node = t&15, k-range = (t>>4)*64 .. +63)
    {
        const int node_l = t & 15;
        const int kb = (t >> 4) * 64;
        const int node = n0 + node_l;
        const int ni = node >> 6, nj = node & 63;
        float s = 0.0f;
#pragma unroll
        for (int g = 0; g < 8; ++g) {
            union { _Float16 h[8]; f16x8 v; } u;
#pragma unroll
            for (int e = 0; e < 8; ++e) {
                int m = bmu_s[kb + g * 8 + e];
                int di = ni - (m >> 6); di = di < 0 ? -di : di;
                int dj = nj - (m & 63); dj = dj < 0 ? -dj : dj;
                _Float16 h = T2h[di * 64 + dj];
                u.h[e] = h;
                s += (float)h;
            }
            *(f16x8*)&As[node_l][kb + g * 8] = u.v;
        }
        atomicAdd(&Sv[node_l], s);
    }
    __syncthreads();
    // phase 2: K-loop, no barriers
    const int wave = t >> 6, lane = t & 63;
    const int lm = lane & 15, quad = lane >> 4;
    const int dbase = wave * 64;
    floatx4 acc[4] = {};
    const _Float16* xt0 = XT + (size_t)(dbase + lm) * BATCH + quad * 8;
#pragma unroll 4
    for (int c = 0; c < 32; ++c) {
        const int k0 = c * 32;
        f16x8 a = *(f16x8*)&As[lm][k0 + quad * 8];
#pragma unroll
        for (int j = 0; j < 4; ++j) {
            f16x8 b = *(const f16x8*)&xt0[(size_t)(j * 16) * BATCH + k0];
            acc[j] = __builtin_amdgcn_mfma_f32_16x16x32_f16(a, b, acc[j], 0, 0, 0);
        }
    }
    const float invB = 1.0f / (float)BATCH;
#pragma unroll
    for (int j = 0; j < 4; ++j) {
        const int col = dbase + j * 16 + lm;
#pragma unroll
        for (int r = 0; r < 4; ++r) {
            const int nr = quad * 4 + r;
            const float cc = 1.0f - Sv[nr] * invB;
            out0[(size_t)(n0 + nr) * FEATS + col] =
                Wm[(size_t)(n0 + nr) * FEATS + col] * cc + acc[j][r] * invB;
        }
    }
}

extern "C" void kernel_launch(void* const* d_in, const int* in_sizes, int n_in,
                              void* d_out, int out_size, void* d_ws, size_t ws_size,
                              hipStream_t stream) {
    const float* X = (const float*)d_in[0];    // (1024, 256)
    const float* Wm = (const float*)d_in[1];   // (4096, 256)
    const int* itp = (const int*)d_in[2];      // scalar iteration
    float* out0 = (float*)d_out;
    float* out1 = out0 + (size_t)NODES * FEATS;

    char* ws = (char*)d_ws;
    unsigned long long* gmin = (unsigned long long*)(ws + 0);  // 8 KB
    _Float16* XT = (_Float16*)(ws + 8192);                     // 512 KB

    hipMemsetAsync(gmin, 0xFF, 1024 * sizeof(unsigned long long), stream);
    k_gemm1min<<<576, 256, 0, stream>>>(X, Wm, gmin, XT);
    k_gemm2d<<<256, 256, 0, stream>>>(gmin, itp, XT, Wm, out0, out1);
}

// Round 9
// 97.042 us; speedup vs baseline: 1.0225x; 1.0225x over previous
//
#include <hip/hip_runtime.h>
#include <math.h>

#define NODES 4096
#define FEATS 256
#define BATCH 1024
#define LR_C 0.5f
#define SIGMA_C 70.4f

typedef _Float16 f16x8 __attribute__((ext_vector_type(8)));
typedef float floatx4 __attribute__((ext_vector_type(4)));

__device__ __forceinline__ void get_params(int it, float& lr, float& r2, float& i2r2) {
    float decay = __expf(-(float)it * (SIGMA_C / 100000.0f));
    float radius = SIGMA_C * decay + 1e-6f;
    lr = LR_C * decay;
    r2 = radius * radius;
    i2r2 = 1.0f / (2.0f * r2);
}

// monotone float -> uint key; u64 key = (fkey << 32) | idx (ties -> smaller idx)
__device__ __forceinline__ unsigned fkey(float f) {
    unsigned u = __float_as_uint(f);
    return (u & 0x80000000u) ? ~u : (u | 0x80000000u);
}
__device__ __forceinline__ unsigned long long shfl_xor_u64(unsigned long long v, int mask) {
    unsigned lo = (unsigned)v, hi = (unsigned)(v >> 32);
    lo = __shfl_xor(lo, mask, 64);
    hi = __shfl_xor(hi, mask, 64);
    return ((unsigned long long)hi << 32) | lo;
}

// ---- K1: W -> fp16 hi/lo + w2 (all 512 blocks); X -> fp16 hi/lo b-major + hi d-major
//          (blocks 0..63); gmin init (blocks 0..3).  [identical to round 6]
__global__ __launch_bounds__(256) void k_prep(const float* __restrict__ Wm, const float* __restrict__ X,
                                              _Float16* __restrict__ Whi, _Float16* __restrict__ Wlo,
                                              float* __restrict__ w2,
                                              _Float16* __restrict__ Xhi, _Float16* __restrict__ Xlo,
                                              _Float16* __restrict__ XT,
                                              unsigned long long* __restrict__ gmin) {
    __shared__ _Float16 T[64][72];
    const int t = threadIdx.x;
    const int blk = blockIdx.x;
    const int wave = t >> 6, lane = t & 63;
#pragma unroll
    for (int rr = 0; rr < 2; ++rr) {
        int row = blk * 8 + wave * 2 + rr;
        float4 v = *(const float4*)&Wm[(size_t)row * FEATS + lane * 4];
        union { _Float16 h[4]; float2 f2; } uh, ul;
        uh.h[0] = (_Float16)v.x; uh.h[1] = (_Float16)v.y;
        uh.h[2] = (_Float16)v.z; uh.h[3] = (_Float16)v.w;
        ul.h[0] = (_Float16)(v.x - (float)uh.h[0]);
        ul.h[1] = (_Float16)(v.y - (float)uh.h[1]);
        ul.h[2] = (_Float16)(v.z - (float)uh.h[2]);
        ul.h[3] = (_Float16)(v.w - (float)uh.h[3]);
        *(float2*)&Whi[(size_t)row * FEATS + lane * 4] = uh.f2;
        *(float2*)&Wlo[(size_t)row * FEATS + lane * 4] = ul.f2;
        float s = v.x * v.x + v.y * v.y + v.z * v.z + v.w * v.w;
#pragma unroll
        for (int off = 32; off > 0; off >>= 1) s += __shfl_down(s, off, 64);
        if (lane == 0) w2[row] = s;
    }
    if (blk < 4) gmin[blk * 256 + t] = 0xFFFFFFFFFFFFFFFFULL;
    if (blk < 64) {
        const int b0 = (blk & 15) * 64, d0 = (blk >> 4) * 64;
        {
            const int bl = t >> 2, dq = (t & 3) * 16;
            union { _Float16 h[16]; float4 q[2]; } uh, ul;
#pragma unroll
            for (int c = 0; c < 4; ++c) {
                float4 v = *(const float4*)&X[(size_t)(b0 + bl) * FEATS + d0 + dq + c * 4];
                uh.h[c * 4 + 0] = (_Float16)v.x; uh.h[c * 4 + 1] = (_Float16)v.y;
                uh.h[c * 4 + 2] = (_Float16)v.z; uh.h[c * 4 + 3] = (_Float16)v.w;
                ul.h[c * 4 + 0] = (_Float16)(v.x - (float)uh.h[c * 4 + 0]);
                ul.h[c * 4 + 1] = (_Float16)(v.y - (float)uh.h[c * 4 + 1]);
                ul.h[c * 4 + 2] = (_Float16)(v.z - (float)uh.h[c * 4 + 2]);
                ul.h[c * 4 + 3] = (_Float16)(v.w - (float)uh.h[c * 4 + 3]);
            }
            *(float4*)&Xhi[(size_t)(b0 + bl) * FEATS + d0 + dq] = uh.q[0];
            *(float4*)&Xhi[(size_t)(b0 + bl) * FEATS + d0 + dq + 8] = uh.q[1];
            *(float4*)&Xlo[(size_t)(b0 + bl) * FEATS + d0 + dq] = ul.q[0];
            *(float4*)&Xlo[(size_t)(b0 + bl) * FEATS + d0 + dq + 8] = ul.q[1];
#pragma unroll
            for (int c = 0; c < 16; ++c) T[bl][dq + c] = uh.h[c];
        }
        __syncthreads();
        {
            const int dl = t >> 2, bq = (t & 3) * 16;
            union { _Float16 h[16]; float4 q[2]; } u;
#pragma unroll
            for (int c = 0; c < 16; ++c) u.h[c] = T[bq + c][dl];
            *(float4*)&XT[(size_t)(d0 + dl) * BATCH + b0 + bq] = u.q[0];
            *(float4*)&XT[(size_t)(d0 + dl) * BATCH + b0 + bq + 8] = u.q[1];
        }
    }
}

// ---- K2: fp32-accurate sqd via fp16-split MFMA (xh*wh + xh*wl + xl*wh), pre-split
//          inputs, 128b x 64n tile (grid 64x8 = 512 blocks, 2/CU), per-row in-wave
//          min -> packed-u64 atomicMin(gmin). 24 MFMA : 12 ds_read_b128 per chunk.
__global__ __launch_bounds__(256) void k_gemm1min(const _Float16* __restrict__ Xhi, const _Float16* __restrict__ Xlo,
                                                  const _Float16* __restrict__ Whi, const _Float16* __restrict__ Wlo,
                                                  const float* __restrict__ w2,
                                                  unsigned long long* __restrict__ gmin) {
    __shared__ _Float16 Ah[128][40];
    __shared__ _Float16 Al[128][40];
    __shared__ _Float16 Bh[64][40];
    __shared__ _Float16 Bl[64][40];
    const int n0 = blockIdx.x * 64;
    const int b0 = blockIdx.y * 128;
    const int t = threadIdx.x;
    const int wave = t >> 6, lane = t & 63;
    const int lm = lane & 15, quad = lane >> 4;
    const int arow = t >> 1, ako = (t & 1) * 16;   // A: 128 rows x 2 threads (16 k each)
    const int brow = t >> 2, bko = (t & 3) * 8;    // B: 64 rows x 4 threads (8 k each)
    floatx4 acc[2][4] = {};
    for (int k0 = 0; k0 < FEATS; k0 += 32) {
        *(float4*)&Ah[arow][ako]     = *(const float4*)&Xhi[(size_t)(b0 + arow) * FEATS + k0 + ako];
        *(float4*)&Ah[arow][ako + 8] = *(const float4*)&Xhi[(size_t)(b0 + arow) * FEATS + k0 + ako + 8];
        *(float4*)&Al[arow][ako]     = *(const float4*)&Xlo[(size_t)(b0 + arow) * FEATS + k0 + ako];
        *(float4*)&Al[arow][ako + 8] = *(const float4*)&Xlo[(size_t)(b0 + arow) * FEATS + k0 + ako + 8];
        *(float4*)&Bh[brow][bko] = *(const float4*)&Whi[(size_t)(n0 + brow) * FEATS + k0 + bko];
        *(float4*)&Bl[brow][bko] = *(const float4*)&Wlo[(size_t)(n0 + brow) * FEATS + k0 + bko];
        __syncthreads();
        f16x8 ah[2], al[2], bh[4], bl[4];
#pragma unroll
        for (int i = 0; i < 2; ++i) {
            ah[i] = *(f16x8*)&Ah[wave * 32 + i * 16 + lm][quad * 8];
            al[i] = *(f16x8*)&Al[wave * 32 + i * 16 + lm][quad * 8];
        }
#pragma unroll
        for (int j = 0; j < 4; ++j) {
            bh[j] = *(f16x8*)&Bh[j * 16 + lm][quad * 8];
            bl[j] = *(f16x8*)&Bl[j * 16 + lm][quad * 8];
        }
#pragma unroll
        for (int i = 0; i < 2; ++i)
#pragma unroll
            for (int j = 0; j < 4; ++j) {
                acc[i][j] = __builtin_amdgcn_mfma_f32_16x16x32_f16(ah[i], bh[j], acc[i][j], 0, 0, 0);
                acc[i][j] = __builtin_amdgcn_mfma_f32_16x16x32_f16(ah[i], bl[j], acc[i][j], 0, 0, 0);
                acc[i][j] = __builtin_amdgcn_mfma_f32_16x16x32_f16(al[i], bh[j], acc[i][j], 0, 0, 0);
            }
        __syncthreads();
    }
    float w2c[4];
#pragma unroll
    for (int j = 0; j < 4; ++j) w2c[j] = w2[n0 + j * 16 + lm];
#pragma unroll
    for (int i = 0; i < 2; ++i)
#pragma unroll
        for (int r = 0; r < 4; ++r) {
            const int row = b0 + wave * 32 + i * 16 + quad * 4 + r;
            unsigned long long m = 0xFFFFFFFFFFFFFFFFULL;
#pragma unroll
            for (int j = 0; j < 4; ++j) {
                float v = w2c[j] - 2.0f * acc[i][j][r];
                unsigned long long k = ((unsigned long long)fkey(v) << 32) | (unsigned)(n0 + j * 16 + lm);
                if (k < m) m = k;
            }
#pragma unroll
            for (int mk = 1; mk < 16; mk <<= 1) {
                unsigned long long o = shfl_xor_u64(m, mk);
                if (o < m) m = o;
            }
            if (lm == 0) atomicMin(&gmin[row], m);
        }
}

// ---- K3: bmu extraction from gmin (+out1 in blocks 0..3), lr_op^T fp16 + Svec.
//          [identical to round 6]
__global__ __launch_bounds__(256) void k_lropB(const unsigned long long* __restrict__ gmin,
                                               const int* __restrict__ itp,
                                               _Float16* __restrict__ lrT, float* __restrict__ Svec,
                                               float* __restrict__ out1) {
    __shared__ int bmu_s[1024];
    __shared__ float texp[64];
    __shared__ float red4[4];
    const int t = threadIdx.x;
    const int blk = blockIdx.x;
#pragma unroll
    for (int j = 0; j < 4; ++j)
        bmu_s[t + j * 256] = (int)(gmin[t + j * 256] & 0xFFFFFFFFULL);
    float lr, r2, i2r2;
    get_params(itp[0], lr, r2, i2r2);
    if (t < 64) texp[t] = __expf(-(float)(t * t) * i2r2);
    __syncthreads();
    if (blk < 4) out1[blk * 256 + t] = (float)bmu_s[blk * 256 + t];
    const int n = blk * 2 + (t >> 7);
    const int b0 = (t & 127) * 8;
    const int ni = n >> 6, nj = n & 63;
    float s = 0.0f;
    union { _Float16 h[8]; float4 q; } u;
#pragma unroll
    for (int c = 0; c < 8; ++c) {
        int m = bmu_s[b0 + c];
        int di = ni - (m >> 6); di = di < 0 ? -di : di;
        int dj = nj - (m & 63); dj = dj < 0 ? -dj : dj;
        int d2 = di * di + dj * dj;
        float val = ((float)d2 <= r2) ? lr * texp[di] * texp[dj] : 0.0f;
        u.h[c] = (_Float16)val;
        s += val;
    }
    *(float4*)&lrT[(size_t)n * BATCH + b0] = u.q;
    const int lane = t & 63, wave = t >> 6;
#pragma unroll
    for (int off = 32; off > 0; off >>= 1) s += __shfl_down(s, off, 64);
    if (lane == 0) red4[wave] = s;
    __syncthreads();
    if (t < 2) Svec[blk * 2 + t] = red4[2 * t] + red4[2 * t + 1];
}

// ---- K4: fp16-MFMA GEMM (lr_op^T @ x), 32n x 64d tile, BK=128 (8 MFMA/barrier),
//          fused combine epilogue: out0 = Wm*(1 - Svec/B) + acc/B. [identical to round 6]
__global__ __launch_bounds__(256) void k_gemm2c(const _Float16* __restrict__ lrT, const _Float16* __restrict__ XT,
                                                const float* __restrict__ Svec, const float* __restrict__ Wm,
                                                float* __restrict__ out0) {
    __shared__ _Float16 As[32][136];
    __shared__ _Float16 Bs[64][136];
    __shared__ float Svl[32];
    const int d0 = blockIdx.x * 64;
    const int n0 = blockIdx.y * 32;
    const int t = threadIdx.x;
    const int wave = t >> 6, lane = t & 63;
    const int wm = wave & 1, wn = wave >> 1;
    const int lm = lane & 15, quad = lane >> 4;
    if (t < 32) Svl[t] = Svec[n0 + t];
    const int arow = t >> 3, acoff = (t & 7) * 16;
    const int brow = t >> 2, bcoff = (t & 3) * 32;
    floatx4 acc0 = {}, acc1 = {};
    for (int k0 = 0; k0 < BATCH; k0 += 128) {
        *(float4*)&As[arow][acoff] = *(const float4*)&lrT[(size_t)(n0 + arow) * BATCH + k0 + acoff];
        *(float4*)&As[arow][acoff + 8] = *(const float4*)&lrT[(size_t)(n0 + arow) * BATCH + k0 + acoff + 8];
#pragma unroll
        for (int c = 0; c < 4; ++c)
            *(float4*)&Bs[brow][bcoff + c * 8] =
                *(const float4*)&XT[(size_t)(d0 + brow) * BATCH + k0 + bcoff + c * 8];
        __syncthreads();
#pragma unroll
        for (int ks = 0; ks < 128; ks += 32) {
            f16x8 a = *(f16x8*)&As[wm * 16 + lm][ks + quad * 8];
            f16x8 b0 = *(f16x8*)&Bs[wn * 32 + lm][ks + quad * 8];
            f16x8 b1 = *(f16x8*)&Bs[wn * 32 + 16 + lm][ks + quad * 8];
            acc0 = __builtin_amdgcn_mfma_f32_16x16x32_f16(a, b0, acc0, 0, 0, 0);
            acc1 = __builtin_amdgcn_mfma_f32_16x16x32_f16(a, b1, acc1, 0, 0, 0);
        }
        __syncthreads();
    }
    const float invB = 1.0f / (float)BATCH;
#pragma unroll
    for (int r = 0; r < 4; ++r) {
        int rowN = n0 + wm * 16 + quad * 4 + r;
        float cc = 1.0f - Svl[rowN - n0] * invB;
        int col0 = d0 + wn * 32 + lm;
        int col1 = col0 + 16;
        out0[(size_t)rowN * FEATS + col0] = Wm[(size_t)rowN * FEATS + col0] * cc + acc0[r] * invB;
        out0[(size_t)rowN * FEATS + col1] = Wm[(size_t)rowN * FEATS + col1] * cc + acc1[r] * invB;
    }
}

extern "C" void kernel_launch(void* const* d_in, const int* in_sizes, int n_in,
                              void* d_out, int out_size, void* d_ws, size_t ws_size,
                              hipStream_t stream) {
    const float* X = (const float*)d_in[0];    // (1024, 256)
    const float* Wm = (const float*)d_in[1];   // (4096, 256)
    const int* itp = (const int*)d_in[2];      // scalar iteration
    float* out0 = (float*)d_out;
    float* out1 = out0 + (size_t)NODES * FEATS;

    char* ws = (char*)d_ws;
    float* w2       = (float*)(ws + 0);              // 16 KB
    _Float16* Xhi   = (_Float16*)(ws + 16384);       // 512 KB
    _Float16* Xlo   = (_Float16*)(ws + 540672);      // 512 KB
    _Float16* XT    = (_Float16*)(ws + 1064960);     // 512 KB
    _Float16* Whi   = (_Float16*)(ws + 1589248);     // 2 MB
    _Float16* Wlo   = (_Float16*)(ws + 3686400);     // 2 MB
    unsigned long long* gmin = (unsigned long long*)(ws + 5783552);  // 8 KB
    float* Svec     = (float*)(ws + 5791744);        // 16 KB
    _Float16* lrT   = (_Float16*)(ws + 5808128);     // 8 MB

    k_prep<<<512, 256, 0, stream>>>(Wm, X, Whi, Wlo, w2, Xhi, Xlo, XT, gmin);
    k_gemm1min<<<dim3(64, 8), 256, 0, stream>>>(Xhi, Xlo, Whi, Wlo, w2, gmin);
    k_lropB<<<2048, 256, 0, stream>>>(gmin, itp, lrT, Svec, out1);
    k_gemm2c<<<dim3(4, 128), 256, 0, stream>>>(lrT, XT, Svec, Wm, out0);
}

// Round 10
// 96.266 us; speedup vs baseline: 1.0308x; 1.0081x over previous
//
#include <hip/hip_runtime.h>
#include <math.h>

#define NODES 4096
#define FEATS 256
#define BATCH 1024
#define LR_C 0.5f
#define SIGMA_C 70.4f

typedef _Float16 f16x8 __attribute__((ext_vector_type(8)));
typedef float floatx4 __attribute__((ext_vector_type(4)));

__device__ __forceinline__ void get_params(int it, float& lr, float& r2, float& i2r2) {
    float decay = __expf(-(float)it * (SIGMA_C / 100000.0f));
    float radius = SIGMA_C * decay + 1e-6f;
    lr = LR_C * decay;
    r2 = radius * radius;
    i2r2 = 1.0f / (2.0f * r2);
}

// monotone float -> uint key; u64 key = (fkey << 32) | idx (ties -> smaller idx)
__device__ __forceinline__ unsigned fkey(float f) {
    unsigned u = __float_as_uint(f);
    return (u & 0x80000000u) ? ~u : (u | 0x80000000u);
}
__device__ __forceinline__ unsigned long long shfl_xor_u64(unsigned long long v, int mask) {
    unsigned lo = (unsigned)v, hi = (unsigned)(v >> 32);
    lo = __shfl_xor(lo, mask, 64);
    hi = __shfl_xor(hi, mask, 64);
    return ((unsigned long long)hi << 32) | lo;
}

// ---- K1: W -> fp16 hi/lo + w2 (all 512 blocks); X -> fp16 hi/lo b-major + hi d-major
//          (blocks 0..63); gmin init (blocks 0..3).
__global__ __launch_bounds__(256) void k_prep(const float* __restrict__ Wm, const float* __restrict__ X,
                                              _Float16* __restrict__ Whi, _Float16* __restrict__ Wlo,
                                              float* __restrict__ w2,
                                              _Float16* __restrict__ Xhi, _Float16* __restrict__ Xlo,
                                              _Float16* __restrict__ XT,
                                              unsigned long long* __restrict__ gmin) {
    __shared__ _Float16 T[64][72];
    const int t = threadIdx.x;
    const int blk = blockIdx.x;
    const int wave = t >> 6, lane = t & 63;
#pragma unroll
    for (int rr = 0; rr < 2; ++rr) {
        int row = blk * 8 + wave * 2 + rr;
        float4 v = *(const float4*)&Wm[(size_t)row * FEATS + lane * 4];
        union { _Float16 h[4]; float2 f2; } uh, ul;
        uh.h[0] = (_Float16)v.x; uh.h[1] = (_Float16)v.y;
        uh.h[2] = (_Float16)v.z; uh.h[3] = (_Float16)v.w;
        ul.h[0] = (_Float16)(v.x - (float)uh.h[0]);
        ul.h[1] = (_Float16)(v.y - (float)uh.h[1]);
        ul.h[2] = (_Float16)(v.z - (float)uh.h[2]);
        ul.h[3] = (_Float16)(v.w - (float)uh.h[3]);
        *(float2*)&Whi[(size_t)row * FEATS + lane * 4] = uh.f2;
        *(float2*)&Wlo[(size_t)row * FEATS + lane * 4] = ul.f2;
        float s = v.x * v.x + v.y * v.y + v.z * v.z + v.w * v.w;
#pragma unroll
        for (int off = 32; off > 0; off >>= 1) s += __shfl_down(s, off, 64);
        if (lane == 0) w2[row] = s;
    }
    if (blk < 4) gmin[blk * 256 + t] = 0xFFFFFFFFFFFFFFFFULL;
    if (blk < 64) {
        const int b0 = (blk & 15) * 64, d0 = (blk >> 4) * 64;
        {
            const int bl = t >> 2, dq = (t & 3) * 16;
            union { _Float16 h[16]; float4 q[2]; } uh, ul;
#pragma unroll
            for (int c = 0; c < 4; ++c) {
                float4 v = *(const float4*)&X[(size_t)(b0 + bl) * FEATS + d0 + dq + c * 4];
                uh.h[c * 4 + 0] = (_Float16)v.x; uh.h[c * 4 + 1] = (_Float16)v.y;
                uh.h[c * 4 + 2] = (_Float16)v.z; uh.h[c * 4 + 3] = (_Float16)v.w;
                ul.h[c * 4 + 0] = (_Float16)(v.x - (float)uh.h[c * 4 + 0]);
                ul.h[c * 4 + 1] = (_Float16)(v.y - (float)uh.h[c * 4 + 1]);
                ul.h[c * 4 + 2] = (_Float16)(v.z - (float)uh.h[c * 4 + 2]);
                ul.h[c * 4 + 3] = (_Float16)(v.w - (float)uh.h[c * 4 + 3]);
            }
            *(float4*)&Xhi[(size_t)(b0 + bl) * FEATS + d0 + dq] = uh.q[0];
            *(float4*)&Xhi[(size_t)(b0 + bl) * FEATS + d0 + dq + 8] = uh.q[1];
            *(float4*)&Xlo[(size_t)(b0 + bl) * FEATS + d0 + dq] = ul.q[0];
            *(float4*)&Xlo[(size_t)(b0 + bl) * FEATS + d0 + dq + 8] = ul.q[1];
#pragma unroll
            for (int c = 0; c < 16; ++c) T[bl][dq + c] = uh.h[c];
        }
        __syncthreads();
        {
            const int dl = t >> 2, bq = (t & 3) * 16;
            union { _Float16 h[16]; float4 q[2]; } u;
#pragma unroll
            for (int c = 0; c < 16; ++c) u.h[c] = T[bq + c][dl];
            *(float4*)&XT[(size_t)(d0 + dl) * BATCH + b0 + bq] = u.q[0];
            *(float4*)&XT[(size_t)(d0 + dl) * BATCH + b0 + bq + 8] = u.q[1];
        }
    }
}

// ---- K2: fp32-accurate sqd via fp16-split MFMA (xh*wh + xh*wl + xl*wh),
//          per-row packed-u64 atomicMin -> gmin. No Sd materialization.
__global__ __launch_bounds__(256) void k_gemm1min(const _Float16* __restrict__ Xhi, const _Float16* __restrict__ Xlo,
                                                  const _Float16* __restrict__ Whi, const _Float16* __restrict__ Wlo,
                                                  const float* __restrict__ w2,
                                                  unsigned long long* __restrict__ gmin) {
    __shared__ _Float16 Ah[64][40];
    __shared__ _Float16 Al[64][40];
    __shared__ _Float16 Bh[64][40];
    __shared__ _Float16 Bl[64][40];
    __shared__ unsigned long long rowmin[64][2];
    const int n0 = blockIdx.x * 64;
    const int b0 = blockIdx.y * 64;
    const int t = threadIdx.x;
    const int wave = t >> 6, lane = t & 63;
    const int wm = wave & 1, wn = wave >> 1;
    const int lm = lane & 15, quad = lane >> 4;
    const int srow = t >> 2, skoff = (t & 3) * 8;
    floatx4 acc[2][2] = {};
    for (int k0 = 0; k0 < FEATS; k0 += 32) {
        *(float4*)&Ah[srow][skoff] = *(const float4*)&Xhi[(size_t)(b0 + srow) * FEATS + k0 + skoff];
        *(float4*)&Al[srow][skoff] = *(const float4*)&Xlo[(size_t)(b0 + srow) * FEATS + k0 + skoff];
        *(float4*)&Bh[srow][skoff] = *(const float4*)&Whi[(size_t)(n0 + srow) * FEATS + k0 + skoff];
        *(float4*)&Bl[srow][skoff] = *(const float4*)&Wlo[(size_t)(n0 + srow) * FEATS + k0 + skoff];
        __syncthreads();
        f16x8 ah[2], al[2], bh[2], bl[2];
        ah[0] = *(f16x8*)&Ah[wm * 32 + lm][quad * 8];
        ah[1] = *(f16x8*)&Ah[wm * 32 + 16 + lm][quad * 8];
        al[0] = *(f16x8*)&Al[wm * 32 + lm][quad * 8];
        al[1] = *(f16x8*)&Al[wm * 32 + 16 + lm][quad * 8];
        bh[0] = *(f16x8*)&Bh[wn * 32 + lm][quad * 8];
        bh[1] = *(f16x8*)&Bh[wn * 32 + 16 + lm][quad * 8];
        bl[0] = *(f16x8*)&Bl[wn * 32 + lm][quad * 8];
        bl[1] = *(f16x8*)&Bl[wn * 32 + 16 + lm][quad * 8];
#pragma unroll
        for (int i = 0; i < 2; ++i)
#pragma unroll
            for (int j = 0; j < 2; ++j) {
                acc[i][j] = __builtin_amdgcn_mfma_f32_16x16x32_f16(ah[i], bh[j], acc[i][j], 0, 0, 0);
                acc[i][j] = __builtin_amdgcn_mfma_f32_16x16x32_f16(ah[i], bl[j], acc[i][j], 0, 0, 0);
                acc[i][j] = __builtin_amdgcn_mfma_f32_16x16x32_f16(al[i], bh[j], acc[i][j], 0, 0, 0);
            }
        __syncthreads();
    }
    const int col0 = n0 + wn * 32 + lm, col1 = col0 + 16;
    const float w20 = w2[col0], w21 = w2[col1];
#pragma unroll
    for (int i = 0; i < 2; ++i) {
#pragma unroll
        for (int r = 0; r < 4; ++r) {
            float va = w20 - 2.0f * acc[i][0][r];
            float vb = w21 - 2.0f * acc[i][1][r];
            unsigned long long ka = ((unsigned long long)fkey(va) << 32) | (unsigned)col0;
            unsigned long long kb = ((unsigned long long)fkey(vb) << 32) | (unsigned)col1;
            unsigned long long m = ka < kb ? ka : kb;
#pragma unroll
            for (int mk = 1; mk < 16; mk <<= 1) {
                unsigned long long o = shfl_xor_u64(m, mk);
                if (o < m) m = o;
            }
            if (lm == 0) rowmin[wm * 32 + i * 16 + quad * 4 + r][wn] = m;
        }
    }
    __syncthreads();
    if (t < 64) {
        unsigned long long v = rowmin[t][0];
        if (rowmin[t][1] < v) v = rowmin[t][1];
        atomicMin(&gmin[b0 + t], v);
    }
}

// ---- K3: bmu extraction from gmin (+out1 in blocks 0..3), lr_op^T fp16 + Svec.
__global__ __launch_bounds__(256) void k_lropB(const unsigned long long* __restrict__ gmin,
                                               const int* __restrict__ itp,
                                               _Float16* __restrict__ lrT, float* __restrict__ Svec,
                                               float* __restrict__ out1) {
    __shared__ int bmu_s[1024];
    __shared__ float texp[64];
    __shared__ float red4[4];
    const int t = threadIdx.x;
    const int blk = blockIdx.x;
#pragma unroll
    for (int j = 0; j < 4; ++j)
        bmu_s[t + j * 256] = (int)(gmin[t + j * 256] & 0xFFFFFFFFULL);
    float lr, r2, i2r2;
    get_params(itp[0], lr, r2, i2r2);
    if (t < 64) texp[t] = __expf(-(float)(t * t) * i2r2);
    __syncthreads();
    if (blk < 4) out1[blk * 256 + t] = (float)bmu_s[blk * 256 + t];
    const int n = blk * 2 + (t >> 7);
    const int b0 = (t & 127) * 8;
    const int ni = n >> 6, nj = n & 63;
    float s = 0.0f;
    union { _Float16 h[8]; float4 q; } u;
#pragma unroll
    for (int c = 0; c < 8; ++c) {
        int m = bmu_s[b0 + c];
        int di = ni - (m >> 6); di = di < 0 ? -di : di;
        int dj = nj - (m & 63); dj = dj < 0 ? -dj : dj;
        int d2 = di * di + dj * dj;
        float val = ((float)d2 <= r2) ? lr * texp[di] * texp[dj] : 0.0f;
        u.h[c] = (_Float16)val;
        s += val;
    }
    *(float4*)&lrT[(size_t)n * BATCH + b0] = u.q;
    const int lane = t & 63, wave = t >> 6;
#pragma unroll
    for (int off = 32; off > 0; off >>= 1) s += __shfl_down(s, off, 64);
    if (lane == 0) red4[wave] = s;
    __syncthreads();
    if (t < 2) Svec[blk * 2 + t] = red4[2 * t] + red4[2 * t + 1];
}

// ---- K4: fp16-MFMA GEMM (lr_op^T @ x), 32n x 64d tile, BK=128 (8 MFMA/barrier),
//          fused combine epilogue: out0 = Wm*(1 - Svec/B) + acc/B.
__global__ __launch_bounds__(256) void k_gemm2c(const _Float16* __restrict__ lrT, const _Float16* __restrict__ XT,
                                                const float* __restrict__ Svec, const float* __restrict__ Wm,
                                                float* __restrict__ out0) {
    __shared__ _Float16 As[32][136];
    __shared__ _Float16 Bs[64][136];
    __shared__ float Svl[32];
    const int d0 = blockIdx.x * 64;
    const int n0 = blockIdx.y * 32;
    const int t = threadIdx.x;
    const int wave = t >> 6, lane = t & 63;
    const int wm = wave & 1, wn = wave >> 1;
    const int lm = lane & 15, quad = lane >> 4;
    if (t < 32) Svl[t] = Svec[n0 + t];
    const int arow = t >> 3, acoff = (t & 7) * 16;
    const int brow = t >> 2, bcoff = (t & 3) * 32;
    floatx4 acc0 = {}, acc1 = {};
    for (int k0 = 0; k0 < BATCH; k0 += 128) {
        *(float4*)&As[arow][acoff] = *(const float4*)&lrT[(size_t)(n0 + arow) * BATCH + k0 + acoff];
        *(float4*)&As[arow][acoff + 8] = *(const float4*)&lrT[(size_t)(n0 + arow) * BATCH + k0 + acoff + 8];
#pragma unroll
        for (int c = 0; c < 4; ++c)
            *(float4*)&Bs[brow][bcoff + c * 8] =
                *(const float4*)&XT[(size_t)(d0 + brow) * BATCH + k0 + bcoff + c * 8];
        __syncthreads();
#pragma unroll
        for (int ks = 0; ks < 128; ks += 32) {
            f16x8 a = *(f16x8*)&As[wm * 16 + lm][ks + quad * 8];
            f16x8 b0 = *(f16x8*)&Bs[wn * 32 + lm][ks + quad * 8];
            f16x8 b1 = *(f16x8*)&Bs[wn * 32 + 16 + lm][ks + quad * 8];
            acc0 = __builtin_amdgcn_mfma_f32_16x16x32_f16(a, b0, acc0, 0, 0, 0);
            acc1 = __builtin_amdgcn_mfma_f32_16x16x32_f16(a, b1, acc1, 0, 0, 0);
        }
        __syncthreads();
    }
    const float invB = 1.0f / (float)BATCH;
#pragma unroll
    for (int r = 0; r < 4; ++r) {
        int rowN = n0 + wm * 16 + quad * 4 + r;
        float cc = 1.0f - Svl[rowN - n0] * invB;
        int col0 = d0 + wn * 32 + lm;
        int col1 = col0 + 16;
        out0[(size_t)rowN * FEATS + col0] = Wm[(size_t)rowN * FEATS + col0] * cc + acc0[r] * invB;
        out0[(size_t)rowN * FEATS + col1] = Wm[(size_t)rowN * FEATS + col1] * cc + acc1[r] * invB;
    }
}

extern "C" void kernel_launch(void* const* d_in, const int* in_sizes, int n_in,
                              void* d_out, int out_size, void* d_ws, size_t ws_size,
                              hipStream_t stream) {
    const float* X = (const float*)d_in[0];    // (1024, 256)
    const float* Wm = (const float*)d_in[1];   // (4096, 256)
    const int* itp = (const int*)d_in[2];      // scalar iteration
    float* out0 = (float*)d_out;
    float* out1 = out0 + (size_t)NODES * FEATS;

    char* ws = (char*)d_ws;
    float* w2       = (float*)(ws + 0);              // 16 KB
    _Float16* Xhi   = (_Float16*)(ws + 16384);       // 512 KB
    _Float16* Xlo   = (_Float16*)(ws + 540672);      // 512 KB
    _Float16* XT    = (_Float16*)(ws + 1064960);     // 512 KB
    _Float16* Whi   = (_Float16*)(ws + 1589248);     // 2 MB
    _Float16* Wlo   = (_Float16*)(ws + 3686400);     // 2 MB
    unsigned long long* gmin = (unsigned long long*)(ws + 5783552);  // 8 KB
    float* Svec     = (float*)(ws + 5791744);        // 16 KB
    _Float16* lrT   = (_Float16*)(ws + 5808128);     // 8 MB

    k_prep<<<512, 256, 0, stream>>>(Wm, X, Whi, Wlo, w2, Xhi, Xlo, XT, gmin);
    k_gemm1min<<<dim3(64, 16), 256, 0, stream>>>(Xhi, Xlo, Whi, Wlo, w2, gmin);
    k_lropB<<<2048, 256, 0, stream>>>(gmin, itp, lrT, Svec, out1);
    k_gemm2c<<<dim3(4, 128), 256, 0, stream>>>(lrT, XT, Svec, Wm, out0);
}